// Round 5
// baseline (243.122 us; speedup 1.0000x reference)
//
#include <hip/hip_runtime.h>

// BinarizeLinear: out[65536,1024] = x @ sign(W)^T + bias
// Round 5: m201-style counted-vmcnt 4-phase schedule. 256x256 tile, BK=64,
// 8 waves (2Mx4N), 128KB LDS, 1 block/CU. Per K-tile 4 phases, each:
// {stage piece for kt+1 | ds_read frags(cur) | setprio MFMA x16 | raw s_barrier}.
// Only drains: lgkmcnt(0)+vmcnt(0) at P3-end (publish A ds_writes + B gloads,
// issued >=1 phase earlier). No __syncthreads in main loop. A (x fp32)
// reg-staged with fused cvt into XOR-swizzled LDS; B = sign(W) bf16 prepass
// in d_ws as pre-swizzled 32KB LDS images, staged via global_load_lds.

typedef __bf16 bf16x8 __attribute__((ext_vector_type(8)));
typedef __bf16 bf16x4 __attribute__((ext_vector_type(4)));
typedef float  f32x4  __attribute__((ext_vector_type(4)));

constexpr int Mdim = 65536, Ndim = 1024, Kdim = 1024;
constexpr int BM = 256, BN = 256, BK = 64;
constexpr int NKT = Kdim / BK;                   // 16
constexpr int NWG = (Mdim / BM) * (Ndim / BN);   // 1024

typedef const __attribute__((address_space(1))) char ga_char;
typedef __attribute__((address_space(3))) char lds_char;
__device__ __forceinline__ void gload16(const void* g, void* l) {
    __builtin_amdgcn_global_load_lds((ga_char*)g, (lds_char*)l, 16, 0, 0);
}
__device__ __forceinline__ f32x4 mfma16(bf16x8 a, bf16x8 b, f32x4 c) {
    return __builtin_amdgcn_mfma_f32_16x16x32_bf16(a, b, c, 0, 0, 0);
}
#define BARRIER()    asm volatile("s_barrier" ::: "memory")
#define WAIT_VM0()   asm volatile("s_waitcnt vmcnt(0)" ::: "memory")
#define WAIT_LGKM0() asm volatile("s_waitcnt lgkmcnt(0)" ::: "memory")

// ---- prepass: WS[(colb*16+kt)*16384 + row*64 + (c ^ (row&7))*8] =
//      sign(W[colb*256+row][kt*64 + c*8 .. +8]) bf16 (pre-swizzled LDS image)
__global__ __launch_bounds__(256)
void wprep_kernel(const float* __restrict__ W, __bf16* __restrict__ WS) {
    const int id = blockIdx.x * 256 + threadIdx.x;   // 131072
    const int c  = id & 7;
    const int kt = (id >> 3) & 15;
    const int n  = id >> 7;
    const float* src = W + (size_t)n * Kdim + kt * 64 + c * 8;
    f32x4 a = *(const f32x4*)src;
    f32x4 b = *(const f32x4*)(src + 4);
    bf16x8 o;
#pragma unroll
    for (int e = 0; e < 4; ++e) {
        o[e]     = (__bf16)(float)((a[e] > 0.f) - (a[e] < 0.f));
        o[e + 4] = (__bf16)(float)((b[e] > 0.f) - (b[e] < 0.f));
    }
    const int row  = n & 255;
    const int colb = n >> 8;
    __bf16* dst = WS + (size_t)(colb * 16 + kt) * 16384
                + row * 64 + ((c ^ (row & 7)) * 8);
    *(bf16x8*)dst = o;
}

// ---- main GEMM ----
__global__ __launch_bounds__(512, 2)
void binlin256(const float* __restrict__ X, const __bf16* __restrict__ WS,
               const float* __restrict__ bias, float* __restrict__ out)
{
    __shared__ __align__(16) __bf16 Al[2][BM * BK];   // 2 x 32 KB
    __shared__ __align__(16) __bf16 Bl[2][BN * BK];   // 2 x 32 KB

    const int swz  = (blockIdx.x & 7) * (NWG / 8) + (blockIdx.x >> 3);
    const int colb = swz & 3;
    const int rowb = swz >> 2;
    const int row0 = rowb * BM;

    const int tid  = threadIdx.x;
    const int lane = tid & 63;
    const int wid  = tid >> 6;
    const int wr   = wid >> 2;
    const int wcn  = wid & 3;
    const int fr   = lane & 15;
    const int hq   = lane >> 4;

    // A staging: 512 threads cover a 128x64 fp32 half-tile: 4 thr/row x 16 f
    const int a_r = tid >> 2;          // 0..127 (row within half)
    const int a_c = (tid & 3) * 16;    // float col
    const float* Xb = X + (size_t)(row0 + a_r) * Kdim + a_c;

    const __bf16* WSb = WS + (size_t)colb * 16 * 16384;

    f32x4 rA0[4], rA1[4];

    auto GLA0 = [&](int kt) {
        const float* p = Xb + kt * 64;
#pragma unroll
        for (int q = 0; q < 4; ++q) rA0[q] = *(const f32x4*)(p + q * 4);
    };
    auto GLA1 = [&](int kt) {
        const float* p = Xb + (size_t)128 * Kdim + kt * 64;
#pragma unroll
        for (int q = 0; q < 4; ++q) rA1[q] = *(const f32x4*)(p + q * 4);
    };
    auto DSWA = [&](int buf, int h, f32x4* r) {
        const int row = h * 128 + a_r;
#pragma unroll
        for (int w = 0; w < 2; ++w) {      // 2 x ds_write_b128 (8 bf16 each)
            bf16x8 v;
#pragma unroll
            for (int e = 0; e < 4; ++e) {
                v[e]     = (__bf16)r[w * 2][e];
                v[e + 4] = (__bf16)r[w * 2 + 1][e];
            }
            const int c    = (a_c >> 3) + w;               // 16B slot
            const int byte = row * 128 + ((c ^ (row & 7)) << 4);
            *(bf16x8*)((char*)&Al[buf][0] + byte) = v;
        }
    };
    auto GLB = [&](int buf, int kt) {       // whole B tile, 4 gload16/thread
        const __bf16* s0 = WSb + (size_t)kt * 16384 + wid * 2048 + lane * 8;
#pragma unroll
        for (int i = 0; i < 4; ++i)
            gload16(s0 + i * 512, &Bl[buf][wid * 2048 + i * 512]);
    };

    auto lda = [&](int buf, int i, int ks) -> bf16x8 {
        const int row  = wr * 128 + i * 16 + fr;
        const int byte = row * 128 + (((ks * 4 + hq) ^ (row & 7)) << 4);
        return *(const bf16x8*)((const char*)&Al[buf][0] + byte);
    };
    auto ldb = [&](int buf, int j, int ks) -> bf16x8 {
        const int row  = wcn * 64 + j * 16 + fr;
        const int byte = row * 128 + (((ks * 4 + hq) ^ (row & 7)) << 4);
        return *(const bf16x8*)((const char*)&Bl[buf][0] + byte);
    };

    f32x4 acc[8][4] = {};

    // prologue: stage tile 0 into buf 0, full drain once
    GLA0(0); GLA1(0); GLB(0, 0);
    DSWA(0, 0, rA0); DSWA(0, 1, rA1);      // compiler auto-waits A vmcnt
    __syncthreads();

    int cur = 0;
    for (int kt = 0; kt < NKT; ++kt) {
        const int nxt = cur ^ 1;
        const bool pre = (kt + 1 < NKT);
        bf16x8 a[4], b0[4], b1[4];

        // -- P0: issue A-half0(kt+1); quadrant (i0-3, ks0)
        if (pre) GLA0(kt + 1);
#pragma unroll
        for (int j = 0; j < 4; ++j) b0[j] = ldb(cur, j, 0);
#pragma unroll
        for (int i = 0; i < 4; ++i) a[i] = lda(cur, i, 0);
        __builtin_amdgcn_s_setprio(1);
#pragma unroll
        for (int i = 0; i < 4; ++i)
#pragma unroll
            for (int j = 0; j < 4; ++j)
                acc[i][j] = mfma16(a[i], b0[j], acc[i][j]);
        __builtin_amdgcn_s_setprio(0);
        BARRIER();

        // -- P1: issue A-half1(kt+1); quadrant (i4-7, ks0)
        if (pre) GLA1(kt + 1);
#pragma unroll
        for (int i = 0; i < 4; ++i) a[i] = lda(cur, i + 4, 0);
        __builtin_amdgcn_s_setprio(1);
#pragma unroll
        for (int i = 0; i < 4; ++i)
#pragma unroll
            for (int j = 0; j < 4; ++j)
                acc[i + 4][j] = mfma16(a[i], b0[j], acc[i + 4][j]);
        __builtin_amdgcn_s_setprio(0);
        BARRIER();

        // -- P2: issue B gloads(kt+1) + write A-half0; quadrant (i0-3, ks1)
        if (pre) { GLB(nxt, kt + 1); DSWA(nxt, 0, rA0); }
#pragma unroll
        for (int j = 0; j < 4; ++j) b1[j] = ldb(cur, j, 1);
#pragma unroll
        for (int i = 0; i < 4; ++i) a[i] = lda(cur, i, 1);
        __builtin_amdgcn_s_setprio(1);
#pragma unroll
        for (int i = 0; i < 4; ++i)
#pragma unroll
            for (int j = 0; j < 4; ++j)
                acc[i][j] = mfma16(a[i], b1[j], acc[i][j]);
        __builtin_amdgcn_s_setprio(0);
        BARRIER();

        // -- P3: write A-half1; quadrant (i4-7, ks1); publish for next tile
        if (pre) DSWA(nxt, 1, rA1);
#pragma unroll
        for (int i = 0; i < 4; ++i) a[i] = lda(cur, i + 4, 1);
        __builtin_amdgcn_s_setprio(1);
#pragma unroll
        for (int i = 0; i < 4; ++i)
#pragma unroll
            for (int j = 0; j < 4; ++j)
                acc[i + 4][j] = mfma16(a[i], b1[j], acc[i + 4][j]);
        __builtin_amdgcn_s_setprio(0);
        if (pre) {
            WAIT_LGKM0();   // my A ds_writes committed before barrier
            WAIT_VM0();     // my B gload_lds (issued in P2) committed
        }
        BARRIER();
        cur = nxt;
    }

    // epilogue: C frag (i,j): row = i*16 + hq*4 + r, col = j*16 + fr
    const int orow = row0 + wr * 128 + hq * 4;
    const int ocol = colb * 256 + wcn * 64 + fr;
#pragma unroll
    for (int j = 0; j < 4; ++j) {
        const float bv = bias[ocol + j * 16];
#pragma unroll
        for (int i = 0; i < 8; ++i)
#pragma unroll
            for (int r = 0; r < 4; ++r)
                out[(size_t)(orow + i * 16 + r) * Ndim + (ocol + j * 16)] =
                    acc[i][j][r] + bv;
    }
}

// ---- fallback (ws too small): reg-staged 128x128, inline sign ----
__global__ __launch_bounds__(256)
void binlin_fallback(const float* __restrict__ X, const float* __restrict__ Wf,
                     const float* __restrict__ bias, float* __restrict__ out)
{
    __shared__ __align__(16) __bf16 Al[2][128][32];
    __shared__ __align__(16) __bf16 Bl[2][128][32];
    constexpr int NT = Kdim / 32;
    const int swz  = (blockIdx.x & 7) * (4096 / 8) + (blockIdx.x >> 3);
    const int colb = swz & 7, rowb = swz >> 3;
    const int row0 = rowb * 128, col0 = colb * 128;
    const int tid = threadIdx.x, lane = tid & 63, wid = tid >> 6;
    const int wr = wid >> 1, wc = wid & 1;
    const int sr = tid >> 2, sc = (tid & 3) * 8;
    const float* Xb = X + (size_t)row0 * Kdim;
    const float* Wb = Wf + (size_t)col0 * Kdim;
    f32x4 ra[2][2], rb[2][2];
    auto GL = [&](int k0) {
#pragma unroll
        for (int p = 0; p < 2; ++p) {
            const float* sa = Xb + (size_t)(p * 64 + sr) * Kdim + k0 + sc;
            ra[p][0] = *(const f32x4*)sa; ra[p][1] = *(const f32x4*)(sa + 4);
            const float* sb = Wb + (size_t)(p * 64 + sr) * Kdim + k0 + sc;
            rb[p][0] = *(const f32x4*)sb; rb[p][1] = *(const f32x4*)(sb + 4);
        }
    };
    auto DSW = [&](int buf) {
#pragma unroll
        for (int p = 0; p < 2; ++p) {
            bf16x8 va, vb;
#pragma unroll
            for (int e = 0; e < 4; ++e) {
                va[e] = (__bf16)ra[p][0][e]; va[e + 4] = (__bf16)ra[p][1][e];
                float a = rb[p][0][e], b = rb[p][1][e];
                vb[e] = (__bf16)(float)((a > 0.f) - (a < 0.f));
                vb[e + 4] = (__bf16)(float)((b > 0.f) - (b < 0.f));
            }
            *(bf16x8*)&Al[buf][p * 64 + sr][sc] = va;
            *(bf16x8*)&Bl[buf][p * 64 + sr][sc] = vb;
        }
    };
    f32x4 acc[4][4] = {};
    const int fr = lane & 15, ks = (lane >> 4) * 8;
    auto COMP = [&](int buf) {
        bf16x8 af[4], bf[4];
#pragma unroll
        for (int i = 0; i < 4; ++i) af[i] = *(const bf16x8*)&Al[buf][wr * 64 + fr + i * 16][ks];
#pragma unroll
        for (int j = 0; j < 4; ++j) bf[j] = *(const bf16x8*)&Bl[buf][wc * 64 + fr + j * 16][ks];
#pragma unroll
        for (int i = 0; i < 4; ++i)
#pragma unroll
            for (int j = 0; j < 4; ++j)
                acc[i][j] = mfma16(af[i], bf[j], acc[i][j]);
    };
    GL(0); DSW(0); __syncthreads();
    int cur = 0;
    for (int t = 0; t < NT; ++t) {
        if (t + 1 < NT) GL((t + 1) * 32);
        COMP(cur);
        if (t + 1 < NT) { DSW(cur ^ 1); __syncthreads(); cur ^= 1; }
    }
    const int orow = row0 + wr * 64 + (lane >> 4) * 4;
    const int ocol = col0 + wc * 64 + fr;
#pragma unroll
    for (int j = 0; j < 4; ++j) {
        const float bv = bias[ocol + j * 16];
#pragma unroll
        for (int i = 0; i < 4; ++i)
#pragma unroll
            for (int r = 0; r < 4; ++r)
                out[(size_t)(orow + i * 16 + r) * Ndim + (ocol + j * 16)] = acc[i][j][r] + bv;
    }
}

extern "C" void kernel_launch(void* const* d_in, const int* in_sizes, int n_in,
                              void* d_out, int out_size, void* d_ws, size_t ws_size,
                              hipStream_t stream) {
    const float* x  = (const float*)d_in[0];
    const float* w  = (const float*)d_in[1];
    const float* b  = (const float*)d_in[2];
    float* out      = (float*)d_out;

    constexpr size_t WS_BYTES = (size_t)Ndim * Kdim * sizeof(__bf16);  // 2 MB

    if (ws_size >= WS_BYTES) {
        __bf16* ws = (__bf16*)d_ws;
        wprep_kernel<<<dim3(512), dim3(256), 0, stream>>>(w, ws);
        binlin256<<<dim3(NWG), dim3(512), 0, stream>>>(x, ws, b, out);
    } else {
        binlin_fallback<<<dim3(4096), dim3(256), 0, stream>>>(x, w, b, out);
    }
}

// Round 6
// 233.484 us; speedup vs baseline: 1.0413x; 1.0413x over previous
//
#include <hip/hip_runtime.h>

// BinarizeLinear: out[65536,1024] = x @ sign(W)^T + bias
// Round 6: occupancy fix. BM=128 BN=256 BK=32, 8 waves (512 thr), per-wave
// output 64x64 (acc=64 VGPR) -> __launch_bounds__(512,4) => 2 blocks/CU,
// 4 waves/SIMD. LDS 52 KB: A double-buffered 128x(32+pad) bf16 (80B rows,
// bank-balanced, no XOR), B double-buffered FRAG-LINEAR image (each wave frag
// read = 1KB contiguous, conflict-free) staged via global_load_lds from a
// prepassed sign(W) image in d_ws (1 MB). A (x fp32) reg-staged with fused
// cvt. Simple 1-barrier/tile loop: cross-block overlap hides the drain (m114).

typedef __bf16 bf16x8 __attribute__((ext_vector_type(8)));
typedef float  f32x4  __attribute__((ext_vector_type(4)));

constexpr int Mdim = 65536, Ndim = 1024, Kdim = 1024;
constexpr int BM = 128, BN = 256, BK = 32;
constexpr int NKT = Kdim / BK;                    // 32
constexpr int NWG = (Mdim / BM) * (Ndim / BN);    // 2048
constexpr int AROWB = 80;                         // padded A row stride (bytes)

typedef const __attribute__((address_space(1))) char ga_char;
typedef __attribute__((address_space(3))) char lds_char;
__device__ __forceinline__ void gload16(const void* g, void* l) {
    __builtin_amdgcn_global_load_lds((ga_char*)g, (lds_char*)l, 16, 0, 0);
}
__device__ __forceinline__ f32x4 mfma16(bf16x8 a, bf16x8 b, f32x4 c) {
    return __builtin_amdgcn_mfma_f32_16x16x32_bf16(a, b, c, 0, 0, 0);
}

// ---- prepass: sign(W) -> bf16, frag-linear image ----
// group id = ((colb*32 + kt)*16 + nb)*64 + lane; elem e of group:
//   WS[id*8+e] = sign(W[colb*256 + nb*16 + (lane&15)][kt*32 + (lane>>4)*8 + e])
__global__ __launch_bounds__(256)
void wprep_kernel(const float* __restrict__ W, __bf16* __restrict__ WS) {
    const int id   = blockIdx.x * 256 + threadIdx.x;   // 131072
    const int colb = id >> 15;
    const int kt   = (id >> 10) & 31;
    const int g    = id & 1023;
    const int nb   = g >> 6;
    const int lane = g & 63;
    const int row  = colb * 256 + nb * 16 + (lane & 15);
    const int col  = kt * 32 + (lane >> 4) * 8;
    const float* src = W + (size_t)row * Kdim + col;
    f32x4 a = *(const f32x4*)src;
    f32x4 b = *(const f32x4*)(src + 4);
    bf16x8 o;
#pragma unroll
    for (int e = 0; e < 4; ++e) {
        o[e]     = (__bf16)(float)((a[e] > 0.f) - (a[e] < 0.f));
        o[e + 4] = (__bf16)(float)((b[e] > 0.f) - (b[e] < 0.f));
    }
    *(bf16x8*)(WS + (size_t)id * 8) = o;
}

// ---- main GEMM ----
__global__ __launch_bounds__(512, 4)
void binlin128x256(const float* __restrict__ X, const __bf16* __restrict__ WS,
                   const float* __restrict__ bias, float* __restrict__ out)
{
    __shared__ __align__(16) char Al[2][BM * AROWB];    // 2 x 10 KB
    __shared__ __align__(16) __bf16 Bl[2][BN * BK];     // 2 x 16 KB (frag-linear)

    // T1: bijective chunked XCD swizzle (2048 % 8 == 0), colb fastest
    const int swz  = (blockIdx.x & 7) * (NWG / 8) + (blockIdx.x >> 3);
    const int colb = swz & 3;
    const int rowb = swz >> 2;
    const int row0 = rowb * BM;

    const int tid  = threadIdx.x;
    const int lane = tid & 63;
    const int wid  = tid >> 6;         // 0..7
    const int wr   = wid >> 2;         // M half (64 rows each)
    const int wcn  = wid & 3;          // N quarter (64 cols each)
    const int fr   = lane & 15;
    const int hq   = lane >> 4;        // 0..3

    // A staging: thread t -> row t>>2 (0..127), 8 floats at col (t&3)*8
    const int a_r = tid >> 2;
    const int a_c = (tid & 3) * 8;
    const float* Xb = X + (size_t)(row0 + a_r) * Kdim + a_c;

    // B image: per colb 512KB region; per kt 16KB (frag-linear)
    const __bf16* WSb = WS + (size_t)colb * (Ndim / BN == 4 ? 262144 : 262144);

    f32x4 ra[2];
    auto GLA = [&](int kt) {
        const float* p = Xb + kt * BK;
        ra[0] = *(const f32x4*)p;
        ra[1] = *(const f32x4*)(p + 4);
    };
    auto DSWA = [&](int buf) {         // fused cvt, one ds_write_b128
        bf16x8 v;
#pragma unroll
        for (int e = 0; e < 4; ++e) {
            v[e]     = (__bf16)ra[0][e];
            v[e + 4] = (__bf16)ra[1][e];
        }
        *(bf16x8*)(&Al[buf][a_r * AROWB + a_c * 2]) = v;
    };
    auto GLB = [&](int buf, int kt) {  // 2 x gload16 per thread (16 KB tile)
        const __bf16* s = WSb + (size_t)kt * 8192 + wid * 1024 + lane * 8;
        gload16(s,       &Bl[buf][wid * 1024]);
        gload16(s + 512, &Bl[buf][wid * 1024 + 512]);
    };

    auto lda = [&](int buf, int i) -> bf16x8 {
        const int row = wr * 64 + i * 16 + fr;
        return *(const bf16x8*)(&Al[buf][row * AROWB + hq * 16]);
    };
    auto ldb = [&](int buf, int j) -> bf16x8 {   // contiguous 1KB per wave
        const int nb = wcn * 4 + j;
        return *(const bf16x8*)(&Bl[buf][nb * 512 + lane * 8]);
    };

    f32x4 acc[4][4] = {};

    // prologue
    GLA(0); GLB(0, 0); DSWA(0);
    __syncthreads();

    int cur = 0;
    for (int t = 0; t < NKT; ++t) {
        const int nxt = cur ^ 1;
        const bool pre = (t + 1 < NKT);
        if (pre) { GLA(t + 1); GLB(nxt, t + 1); }   // in flight during COMP

        bf16x8 af[4];
#pragma unroll
        for (int i = 0; i < 4; ++i) af[i] = lda(cur, i);
        __builtin_amdgcn_s_setprio(1);
#pragma unroll
        for (int j = 0; j < 4; ++j) {
            bf16x8 bf = ldb(cur, j);
#pragma unroll
            for (int i = 0; i < 4; ++i)
                acc[i][j] = mfma16(af[i], bf, acc[i][j]);
        }
        __builtin_amdgcn_s_setprio(0);

        if (pre) {
            DSWA(nxt);          // cvt waits its own (old) global loads
            __syncthreads();    // publish nxt; drain hidden by other block
        }
        cur = nxt;
    }

    // epilogue: C row = i*16 + hq*4 + r, col = j*16 + fr
    const int orow = row0 + wr * 64 + hq * 4;
    const int ocol = colb * BN + wcn * 64 + fr;
#pragma unroll
    for (int j = 0; j < 4; ++j) {
        const float bv = bias[ocol + j * 16];
#pragma unroll
        for (int i = 0; i < 4; ++i)
#pragma unroll
            for (int r = 0; r < 4; ++r)
                out[(size_t)(orow + i * 16 + r) * Ndim + (ocol + j * 16)] =
                    acc[i][j][r] + bv;
    }
}

// ---- fallback (ws too small): reg-staged 128x128, inline sign ----
__global__ __launch_bounds__(256)
void binlin_fallback(const float* __restrict__ X, const float* __restrict__ Wf,
                     const float* __restrict__ bias, float* __restrict__ out)
{
    __shared__ __align__(16) __bf16 Al[2][128][32];
    __shared__ __align__(16) __bf16 Bl[2][128][32];
    constexpr int NT = Kdim / 32;
    const int swz  = (blockIdx.x & 7) * (4096 / 8) + (blockIdx.x >> 3);
    const int colb = swz & 7, rowb = swz >> 3;
    const int row0 = rowb * 128, col0 = colb * 128;
    const int tid = threadIdx.x, lane = tid & 63, wid = tid >> 6;
    const int wr = wid >> 1, wc = wid & 1;
    const int sr = tid >> 2, sc = (tid & 3) * 8;
    const float* Xb = X + (size_t)row0 * Kdim;
    const float* Wb = Wf + (size_t)col0 * Kdim;
    f32x4 ra[2][2], rb[2][2];
    auto GL = [&](int k0) {
#pragma unroll
        for (int p = 0; p < 2; ++p) {
            const float* sa = Xb + (size_t)(p * 64 + sr) * Kdim + k0 + sc;
            ra[p][0] = *(const f32x4*)sa; ra[p][1] = *(const f32x4*)(sa + 4);
            const float* sb = Wb + (size_t)(p * 64 + sr) * Kdim + k0 + sc;
            rb[p][0] = *(const f32x4*)sb; rb[p][1] = *(const f32x4*)(sb + 4);
        }
    };
    auto DSW = [&](int buf) {
#pragma unroll
        for (int p = 0; p < 2; ++p) {
            bf16x8 va, vb;
#pragma unroll
            for (int e = 0; e < 4; ++e) {
                va[e] = (__bf16)ra[p][0][e]; va[e + 4] = (__bf16)ra[p][1][e];
                float a = rb[p][0][e], b = rb[p][1][e];
                vb[e] = (__bf16)(float)((a > 0.f) - (a < 0.f));
                vb[e + 4] = (__bf16)(float)((b > 0.f) - (b < 0.f));
            }
            *(bf16x8*)&Al[buf][p * 64 + sr][sc] = va;
            *(bf16x8*)&Bl[buf][p * 64 + sr][sc] = vb;
        }
    };
    f32x4 acc[4][4] = {};
    const int fr = lane & 15, ks = (lane >> 4) * 8;
    auto COMP = [&](int buf) {
        bf16x8 af[4], bf[4];
#pragma unroll
        for (int i = 0; i < 4; ++i) af[i] = *(const bf16x8*)&Al[buf][wr * 64 + fr + i * 16][ks];
#pragma unroll
        for (int j = 0; j < 4; ++j) bf[j] = *(const bf16x8*)&Bl[buf][wc * 64 + fr + j * 16][ks];
#pragma unroll
        for (int i = 0; i < 4; ++i)
#pragma unroll
            for (int j = 0; j < 4; ++j)
                acc[i][j] = mfma16(af[i], bf[j], acc[i][j]);
    };
    GL(0); DSW(0); __syncthreads();
    int cur = 0;
    for (int t = 0; t < NT; ++t) {
        if (t + 1 < NT) GL((t + 1) * 32);
        COMP(cur);
        if (t + 1 < NT) { DSW(cur ^ 1); __syncthreads(); cur ^= 1; }
    }
    const int orow = row0 + wr * 64 + (lane >> 4) * 4;
    const int ocol = col0 + wc * 64 + fr;
#pragma unroll
    for (int j = 0; j < 4; ++j) {
        const float bv = bias[ocol + j * 16];
#pragma unroll
        for (int i = 0; i < 4; ++i)
#pragma unroll
            for (int r = 0; r < 4; ++r)
                out[(size_t)(orow + i * 16 + r) * Ndim + (ocol + j * 16)] = acc[i][j][r] + bv;
    }
}

extern "C" void kernel_launch(void* const* d_in, const int* in_sizes, int n_in,
                              void* d_out, int out_size, void* d_ws, size_t ws_size,
                              hipStream_t stream) {
    const float* x  = (const float*)d_in[0];
    const float* w  = (const float*)d_in[1];
    const float* b  = (const float*)d_in[2];
    float* out      = (float*)d_out;

    constexpr size_t WS_BYTES = (size_t)Ndim * Kdim * sizeof(__bf16);  // 2 MB

    if (ws_size >= WS_BYTES) {
        __bf16* ws = (__bf16*)d_ws;
        wprep_kernel<<<dim3(512), dim3(256), 0, stream>>>(w, ws);
        binlin128x256<<<dim3(NWG), dim3(512), 0, stream>>>(x, ws, b, out);
    } else {
        binlin_fallback<<<dim3(4096), dim3(256), 0, stream>>>(x, w, b, out);
    }
}